// Round 8
// baseline (806.092 us; speedup 1.0000x reference)
//
#include <hip/hip_runtime.h>

// EHD layer: 3x3 x 8-orientation conv -> argmax+threshold -> 9-bin one-hot
// -> 5x5 box count / 25.
// R11 == R8 (best: 655us) launched TWICE back-to-back.
// MEASUREMENT ROUND: dur = F + 2K where F = fixed harness cost (poison fill
// + restores), K = kernel time. K = dur(R11) - 655 identifies K exactly.
// Second launch recomputes identical values (pure function, same input) ->
// absmax 0 preserved. Two plain launches, no sync APIs: graph-capture safe.
//  - kernel body byte-identical to R8 (no NT stores, no burst stash)

#define NOR 8
#define HH  1024
#define WW  1024
#define H2  1018
#define W2  1018
#define SH  64            // output rows per stripe
#define NIT (SH + 4)      // 68 iterations

__global__ __launch_bounds__(512, 2)
void ehd_rows(const float* __restrict__ x,
              const float* __restrict__ masks,
              float* __restrict__ out)
{
    __shared__ unsigned long long oh[2][1024];   // 16 KB, double-buffered

    const int t  = threadIdx.x;
    const int j0 = t * 2;                        // own conv cols j0, j0+1
    const int r0 = blockIdx.x * SH;
    const int b  = blockIdx.y;
    const float* xb = x + (long)b * HH * WW;

    // masks: thread-uniform scalar loads
    float m[NOR][9];
#pragma unroll
    for (int o = 0; o < NOR; ++o)
#pragma unroll
        for (int k = 0; k < 9; ++k)
            m[o][k] = masks[o * 9 + k];

    const bool cvalid = (j0 <= 1020);    // conv cols j0,j0+1 <= 1021 (t<=510)
    const bool ovalid = (j0 <= W2 - 2);  // out cols j0,j0+1 <= 1017 (t<=508)

    // second float2 covers cols j0+2,j0+3; clamp only engages for t=511
    const int jb = (j0 + 2 > WW - 2) ? (WW - 2) : (j0 + 2);

    // register x-window: rows rr..rr+2, cols j0..j0+3
    float wr[3][4];
#pragma unroll
    for (int s = 0; s < 3; ++s) {
        const float2 A = *reinterpret_cast<const float2*>(xb + (r0 + s) * WW + j0);
        const float2 B = *reinterpret_cast<const float2*>(xb + (r0 + s) * WW + jb);
        wr[s][0] = A.x; wr[s][1] = A.y; wr[s][2] = B.x; wr[s][3] = B.y;
    }

    // vertical 5-row ring of horizontal 5-sums, in registers
    unsigned long long hs[5][2];
#pragma unroll
    for (int q = 0; q < 5; ++q) { hs[q][0] = 0ull; hs[q][1] = 0ull; }

    for (int rr = 0; rr < NIT; ++rr) {
        // ---- prefetch x row rr+3 (consumed next iteration)
        int nr = r0 + rr + 3; if (nr > HH - 1) nr = HH - 1;
        const float2 pa = *reinterpret_cast<const float2*>(xb + nr * WW + j0);
        const float2 pb = *reinterpret_cast<const float2*>(xb + nr * WW + jb);

        unsigned long long* ohb = oh[rr & 1];

        // ---- conv -> argmax -> threshold -> packed one-hot (2 cols)
        if (cvalid) {
            unsigned long long ov[2];
#pragma unroll
            for (int c = 0; c < 2; ++c) {
                float best = 0.0f; int bi = 0;
#pragma unroll
                for (int o = 0; o < NOR; ++o) {
                    float acc = wr[0][c] * m[o][0];             // same order as R2/R3/R4
                    acc = fmaf(wr[0][c + 1], m[o][1], acc);
                    acc = fmaf(wr[0][c + 2], m[o][2], acc);
                    acc = fmaf(wr[1][c    ], m[o][3], acc);
                    acc = fmaf(wr[1][c + 1], m[o][4], acc);
                    acc = fmaf(wr[1][c + 2], m[o][5], acc);
                    acc = fmaf(wr[2][c    ], m[o][6], acc);
                    acc = fmaf(wr[2][c + 1], m[o][7], acc);
                    acc = fmaf(wr[2][c + 2], m[o][8], acc);
                    if (o == 0)          { best = acc; }
                    else if (acc > best) { best = acc; bi = o; }
                }
                if (best < 0.9f) bi = NOR;
                ov[c] = 1ull << (7 * bi);
            }
            ulonglong2 wv; wv.x = ov[0]; wv.y = ov[1];
            *reinterpret_cast<ulonglong2*>(&ohb[j0]) = wv;      // 16B aligned
        }
        __syncthreads();

        // ---- horizontal 5-sums + vertical ring + emit
        if (ovalid) {
            const ulonglong2 A  = *reinterpret_cast<const ulonglong2*>(&ohb[j0]);
            const ulonglong2 Bv = *reinterpret_cast<const ulonglong2*>(&ohb[j0 + 2]);
            const ulonglong2 Cv = *reinterpret_cast<const ulonglong2*>(&ohb[j0 + 4]);
            const unsigned long long s0 = A.x + A.y + Bv.x + Bv.y + Cv.x;
            const unsigned long long s1 = s0 - A.x + Cv.y;      // 7-bit fields: exact

#pragma unroll
            for (int q = 0; q < 4; ++q) { hs[q][0] = hs[q + 1][0]; hs[q][1] = hs[q + 1][1]; }
            hs[4][0] = s0; hs[4][1] = s1;

            if (rr >= 4) {
                const int ro = r0 + rr - 4;
                if (ro < H2) {
                    const unsigned long long v0 = hs[0][0] + hs[1][0] + hs[2][0] + hs[3][0] + hs[4][0];
                    const unsigned long long v1 = hs[0][1] + hs[1][1] + hs[2][1] + hs[3][1] + hs[4][1];
                    float* op = out + (long)b * 9 * H2 * W2 + (long)ro * W2 + j0;
#pragma unroll
                    for (int k = 0; k < 9; ++k) {
                        const float f0 = (float)((unsigned)(v0 >> (7 * k)) & 0x7Fu) * (1.0f / 25.0f);
                        const float f1 = (float)((unsigned)(v1 >> (7 * k)) & 0x7Fu) * (1.0f / 25.0f);
                        *reinterpret_cast<float2*>(op + (long)k * H2 * W2) = make_float2(f0, f1);
                    }
                }
            }
        }
        // next iteration writes the OTHER oh buffer; this iteration's barrier
        // orders all reads of ohb before any rewrite two iterations later.

        // ---- rotate register x-window
#pragma unroll
        for (int d = 0; d < 4; ++d) { wr[0][d] = wr[1][d]; wr[1][d] = wr[2][d]; }
        wr[2][0] = pa.x; wr[2][1] = pa.y; wr[2][2] = pb.x; wr[2][3] = pb.y;
    }
}

extern "C" void kernel_launch(void* const* d_in, const int* in_sizes, int n_in,
                              void* d_out, int out_size, void* d_ws, size_t ws_size,
                              hipStream_t stream)
{
    const float* x     = (const float*)d_in[0];
    const float* masks = (const float*)d_in[1];
    float* out         = (float*)d_out;

    dim3 grid(16,    // 16 row stripes of 64 rows (16*64 = 1024 >= 1018)
              16);   // batch
    // MEASUREMENT: launch twice. dur = F + 2K -> K = dur - 655us.
    // Second launch rewrites byte-identical values (pure function of x).
    ehd_rows<<<grid, 512, 0, stream>>>(x, masks, out);
    ehd_rows<<<grid, 512, 0, stream>>>(x, masks, out);
}

// Round 9
// 670.899 us; speedup vs baseline: 1.2015x; 1.2015x over previous
//
#include <hip/hip_runtime.h>

// EHD layer: 3x3 x 8-orientation conv -> argmax+threshold -> 9-bin one-hot
// -> 5x5 box count / 25.
// R12 == R8 with SH 64->32 (single-variable: store-MLP / occupancy).
// R11 measured K ~= 151us kernel vs F ~= 504us fixed harness cost; traffic
// floor is ~105us. R8 ran 1 block/CU (8 waves). Doubling blocks/CU doubles
// in-flight stores; independent per-block barriers let one block's bursts
// cover the other's stalls. Redundancy cost only +6% (36/32 vs 68/64).
//  - kernel body byte-identical to R8 except SH/NIT and grid.x
//  - conv FMA order + argmax tie rule bit-identical (absmax 0)

#define NOR 8
#define HH  1024
#define WW  1024
#define H2  1018
#define W2  1018
#define SH  32            // output rows per stripe
#define NIT (SH + 4)      // 36 iterations

__global__ __launch_bounds__(512, 2)
void ehd_rows(const float* __restrict__ x,
              const float* __restrict__ masks,
              float* __restrict__ out)
{
    __shared__ unsigned long long oh[2][1024];   // 16 KB, double-buffered

    const int t  = threadIdx.x;
    const int j0 = t * 2;                        // own conv cols j0, j0+1
    const int r0 = blockIdx.x * SH;
    const int b  = blockIdx.y;
    const float* xb = x + (long)b * HH * WW;

    // masks: thread-uniform scalar loads
    float m[NOR][9];
#pragma unroll
    for (int o = 0; o < NOR; ++o)
#pragma unroll
        for (int k = 0; k < 9; ++k)
            m[o][k] = masks[o * 9 + k];

    const bool cvalid = (j0 <= 1020);    // conv cols j0,j0+1 <= 1021 (t<=510)
    const bool ovalid = (j0 <= W2 - 2);  // out cols j0,j0+1 <= 1017 (t<=508)

    // second float2 covers cols j0+2,j0+3; clamp only engages for t=511
    const int jb = (j0 + 2 > WW - 2) ? (WW - 2) : (j0 + 2);

    // register x-window: rows rr..rr+2, cols j0..j0+3
    float wr[3][4];
#pragma unroll
    for (int s = 0; s < 3; ++s) {
        const float2 A = *reinterpret_cast<const float2*>(xb + (r0 + s) * WW + j0);
        const float2 B = *reinterpret_cast<const float2*>(xb + (r0 + s) * WW + jb);
        wr[s][0] = A.x; wr[s][1] = A.y; wr[s][2] = B.x; wr[s][3] = B.y;
    }

    // vertical 5-row ring of horizontal 5-sums, in registers
    unsigned long long hs[5][2];
#pragma unroll
    for (int q = 0; q < 5; ++q) { hs[q][0] = 0ull; hs[q][1] = 0ull; }

    for (int rr = 0; rr < NIT; ++rr) {
        // ---- prefetch x row rr+3 (consumed next iteration)
        int nr = r0 + rr + 3; if (nr > HH - 1) nr = HH - 1;
        const float2 pa = *reinterpret_cast<const float2*>(xb + nr * WW + j0);
        const float2 pb = *reinterpret_cast<const float2*>(xb + nr * WW + jb);

        unsigned long long* ohb = oh[rr & 1];

        // ---- conv -> argmax -> threshold -> packed one-hot (2 cols)
        if (cvalid) {
            unsigned long long ov[2];
#pragma unroll
            for (int c = 0; c < 2; ++c) {
                float best = 0.0f; int bi = 0;
#pragma unroll
                for (int o = 0; o < NOR; ++o) {
                    float acc = wr[0][c] * m[o][0];             // same order as R2/R3/R4
                    acc = fmaf(wr[0][c + 1], m[o][1], acc);
                    acc = fmaf(wr[0][c + 2], m[o][2], acc);
                    acc = fmaf(wr[1][c    ], m[o][3], acc);
                    acc = fmaf(wr[1][c + 1], m[o][4], acc);
                    acc = fmaf(wr[1][c + 2], m[o][5], acc);
                    acc = fmaf(wr[2][c    ], m[o][6], acc);
                    acc = fmaf(wr[2][c + 1], m[o][7], acc);
                    acc = fmaf(wr[2][c + 2], m[o][8], acc);
                    if (o == 0)          { best = acc; }
                    else if (acc > best) { best = acc; bi = o; }
                }
                if (best < 0.9f) bi = NOR;
                ov[c] = 1ull << (7 * bi);
            }
            ulonglong2 wv; wv.x = ov[0]; wv.y = ov[1];
            *reinterpret_cast<ulonglong2*>(&ohb[j0]) = wv;      // 16B aligned
        }
        __syncthreads();

        // ---- horizontal 5-sums + vertical ring + emit
        if (ovalid) {
            const ulonglong2 A  = *reinterpret_cast<const ulonglong2*>(&ohb[j0]);
            const ulonglong2 Bv = *reinterpret_cast<const ulonglong2*>(&ohb[j0 + 2]);
            const ulonglong2 Cv = *reinterpret_cast<const ulonglong2*>(&ohb[j0 + 4]);
            const unsigned long long s0 = A.x + A.y + Bv.x + Bv.y + Cv.x;
            const unsigned long long s1 = s0 - A.x + Cv.y;      // 7-bit fields: exact

#pragma unroll
            for (int q = 0; q < 4; ++q) { hs[q][0] = hs[q + 1][0]; hs[q][1] = hs[q + 1][1]; }
            hs[4][0] = s0; hs[4][1] = s1;

            if (rr >= 4) {
                const int ro = r0 + rr - 4;
                if (ro < H2) {
                    const unsigned long long v0 = hs[0][0] + hs[1][0] + hs[2][0] + hs[3][0] + hs[4][0];
                    const unsigned long long v1 = hs[0][1] + hs[1][1] + hs[2][1] + hs[3][1] + hs[4][1];
                    float* op = out + (long)b * 9 * H2 * W2 + (long)ro * W2 + j0;
#pragma unroll
                    for (int k = 0; k < 9; ++k) {
                        const float f0 = (float)((unsigned)(v0 >> (7 * k)) & 0x7Fu) * (1.0f / 25.0f);
                        const float f1 = (float)((unsigned)(v1 >> (7 * k)) & 0x7Fu) * (1.0f / 25.0f);
                        *reinterpret_cast<float2*>(op + (long)k * H2 * W2) = make_float2(f0, f1);
                    }
                }
            }
        }
        // next iteration writes the OTHER oh buffer; this iteration's barrier
        // orders all reads of ohb before any rewrite two iterations later.

        // ---- rotate register x-window
#pragma unroll
        for (int d = 0; d < 4; ++d) { wr[0][d] = wr[1][d]; wr[1][d] = wr[2][d]; }
        wr[2][0] = pa.x; wr[2][1] = pa.y; wr[2][2] = pb.x; wr[2][3] = pb.y;
    }
}

extern "C" void kernel_launch(void* const* d_in, const int* in_sizes, int n_in,
                              void* d_out, int out_size, void* d_ws, size_t ws_size,
                              hipStream_t stream)
{
    const float* x     = (const float*)d_in[0];
    const float* masks = (const float*)d_in[1];
    float* out         = (float*)d_out;

    dim3 grid(32,    // 32 row stripes of 32 rows (32*32 = 1024 >= 1018)
              16);   // batch
    ehd_rows<<<grid, 512, 0, stream>>>(x, masks, out);
}

// Round 10
// 653.215 us; speedup vs baseline: 1.2340x; 1.0271x over previous
//
#include <hip/hip_runtime.h>

// EHD layer: 3x3 x 8-orientation conv -> argmax+threshold -> 9-bin one-hot
// -> 5x5 box count / 25.
// R13 == R8 byte-identical (REVERT TO BEST, 655.1us). Final kernel.
// Session ledger: K ~= 151us kernel (R11 double-launch measurement) vs
// 664 MB traffic floor of ~105us (70% of fill-proven 6.3 TB/s); F ~= 504us
// fixed harness cost (poison fill + restores). Isolated experiments on
// barriers (R4/R7), instr count (R4), NT stores (R9), burst order (R10),
// and occupancy/MLP (R12) were all flat or negative; only stream-count
// reduction (R8) won. Remaining kernel upside <= 46us (~7% of dur):
// intrinsic to the 9-plane strided write pattern. Roofline.
//  - 256 blocks (16 stripes x 16 batch) = 1 block/CU, 512 thr (2 waves/SIMD)
//  - block walks a 64-row stripe sequentially, barrier-lockstep bursts
//  - thread owns 2 cols: float2 x-loads, float2 stores
//  - LDS one-hot halo double-buffered, 1 barrier/iter
//  - conv FMA order + argmax tie rule bit-identical to R2..R12 (absmax 0)

#define NOR 8
#define HH  1024
#define WW  1024
#define H2  1018
#define W2  1018
#define SH  64            // output rows per stripe
#define NIT (SH + 4)      // 68 iterations

__global__ __launch_bounds__(512, 2)
void ehd_rows(const float* __restrict__ x,
              const float* __restrict__ masks,
              float* __restrict__ out)
{
    __shared__ unsigned long long oh[2][1024];   // 16 KB, double-buffered

    const int t  = threadIdx.x;
    const int j0 = t * 2;                        // own conv cols j0, j0+1
    const int r0 = blockIdx.x * SH;
    const int b  = blockIdx.y;
    const float* xb = x + (long)b * HH * WW;

    // masks: thread-uniform scalar loads
    float m[NOR][9];
#pragma unroll
    for (int o = 0; o < NOR; ++o)
#pragma unroll
        for (int k = 0; k < 9; ++k)
            m[o][k] = masks[o * 9 + k];

    const bool cvalid = (j0 <= 1020);    // conv cols j0,j0+1 <= 1021 (t<=510)
    const bool ovalid = (j0 <= W2 - 2);  // out cols j0,j0+1 <= 1017 (t<=508)

    // second float2 covers cols j0+2,j0+3; clamp only engages for t=511
    const int jb = (j0 + 2 > WW - 2) ? (WW - 2) : (j0 + 2);

    // register x-window: rows rr..rr+2, cols j0..j0+3
    float wr[3][4];
#pragma unroll
    for (int s = 0; s < 3; ++s) {
        const float2 A = *reinterpret_cast<const float2*>(xb + (r0 + s) * WW + j0);
        const float2 B = *reinterpret_cast<const float2*>(xb + (r0 + s) * WW + jb);
        wr[s][0] = A.x; wr[s][1] = A.y; wr[s][2] = B.x; wr[s][3] = B.y;
    }

    // vertical 5-row ring of horizontal 5-sums, in registers
    unsigned long long hs[5][2];
#pragma unroll
    for (int q = 0; q < 5; ++q) { hs[q][0] = 0ull; hs[q][1] = 0ull; }

    for (int rr = 0; rr < NIT; ++rr) {
        // ---- prefetch x row rr+3 (consumed next iteration)
        int nr = r0 + rr + 3; if (nr > HH - 1) nr = HH - 1;
        const float2 pa = *reinterpret_cast<const float2*>(xb + nr * WW + j0);
        const float2 pb = *reinterpret_cast<const float2*>(xb + nr * WW + jb);

        unsigned long long* ohb = oh[rr & 1];

        // ---- conv -> argmax -> threshold -> packed one-hot (2 cols)
        if (cvalid) {
            unsigned long long ov[2];
#pragma unroll
            for (int c = 0; c < 2; ++c) {
                float best = 0.0f; int bi = 0;
#pragma unroll
                for (int o = 0; o < NOR; ++o) {
                    float acc = wr[0][c] * m[o][0];             // same order as R2/R3/R4
                    acc = fmaf(wr[0][c + 1], m[o][1], acc);
                    acc = fmaf(wr[0][c + 2], m[o][2], acc);
                    acc = fmaf(wr[1][c    ], m[o][3], acc);
                    acc = fmaf(wr[1][c + 1], m[o][4], acc);
                    acc = fmaf(wr[1][c + 2], m[o][5], acc);
                    acc = fmaf(wr[2][c    ], m[o][6], acc);
                    acc = fmaf(wr[2][c + 1], m[o][7], acc);
                    acc = fmaf(wr[2][c + 2], m[o][8], acc);
                    if (o == 0)          { best = acc; }
                    else if (acc > best) { best = acc; bi = o; }
                }
                if (best < 0.9f) bi = NOR;
                ov[c] = 1ull << (7 * bi);
            }
            ulonglong2 wv; wv.x = ov[0]; wv.y = ov[1];
            *reinterpret_cast<ulonglong2*>(&ohb[j0]) = wv;      // 16B aligned
        }
        __syncthreads();

        // ---- horizontal 5-sums + vertical ring + emit
        if (ovalid) {
            const ulonglong2 A  = *reinterpret_cast<const ulonglong2*>(&ohb[j0]);
            const ulonglong2 Bv = *reinterpret_cast<const ulonglong2*>(&ohb[j0 + 2]);
            const ulonglong2 Cv = *reinterpret_cast<const ulonglong2*>(&ohb[j0 + 4]);
            const unsigned long long s0 = A.x + A.y + Bv.x + Bv.y + Cv.x;
            const unsigned long long s1 = s0 - A.x + Cv.y;      // 7-bit fields: exact

#pragma unroll
            for (int q = 0; q < 4; ++q) { hs[q][0] = hs[q + 1][0]; hs[q][1] = hs[q + 1][1]; }
            hs[4][0] = s0; hs[4][1] = s1;

            if (rr >= 4) {
                const int ro = r0 + rr - 4;
                if (ro < H2) {
                    const unsigned long long v0 = hs[0][0] + hs[1][0] + hs[2][0] + hs[3][0] + hs[4][0];
                    const unsigned long long v1 = hs[0][1] + hs[1][1] + hs[2][1] + hs[3][1] + hs[4][1];
                    float* op = out + (long)b * 9 * H2 * W2 + (long)ro * W2 + j0;
#pragma unroll
                    for (int k = 0; k < 9; ++k) {
                        const float f0 = (float)((unsigned)(v0 >> (7 * k)) & 0x7Fu) * (1.0f / 25.0f);
                        const float f1 = (float)((unsigned)(v1 >> (7 * k)) & 0x7Fu) * (1.0f / 25.0f);
                        *reinterpret_cast<float2*>(op + (long)k * H2 * W2) = make_float2(f0, f1);
                    }
                }
            }
        }
        // next iteration writes the OTHER oh buffer; this iteration's barrier
        // orders all reads of ohb before any rewrite two iterations later.

        // ---- rotate register x-window
#pragma unroll
        for (int d = 0; d < 4; ++d) { wr[0][d] = wr[1][d]; wr[1][d] = wr[2][d]; }
        wr[2][0] = pa.x; wr[2][1] = pa.y; wr[2][2] = pb.x; wr[2][3] = pb.y;
    }
}

extern "C" void kernel_launch(void* const* d_in, const int* in_sizes, int n_in,
                              void* d_out, int out_size, void* d_ws, size_t ws_size,
                              hipStream_t stream)
{
    const float* x     = (const float*)d_in[0];
    const float* masks = (const float*)d_in[1];
    float* out         = (float*)d_out;

    dim3 grid(16,    // 16 row stripes of 64 rows (16*64 = 1024 >= 1018)
              16);   // batch
    ehd_rows<<<grid, 512, 0, stream>>>(x, masks, out);
}